// Round 14
// baseline (137.906 us; speedup 1.0000x reference)
//
#include <hip/hip_runtime.h>
#include <hip/hip_bf16.h>

// Problem dims
constexpr int BDIM = 16384;  // B (GEMM M)
constexpr int LDIM = 4096;   // L (GEMM N)
constexpr int HDIM = 1024;   // H (GEMM K)

// GEMM tile: 256x128, BK=64 (i8), 256 threads = 4 waves (2Mx2N),
// wave tile 128x64 via mfma_i32_32x32x32_i8 (16 MFMA/region vs 32).
// A,B in 3-slot LDS rings, distance-2 staging, vmcnt(6), ONE barrier/K-tile.
// Aq/Wq panel-major tiled + pre-swizzled (R13): staging reads 4KB contiguous.
constexpr int BM = 256;
constexpr int BN = 128;
constexpr int BK = 64;
constexpr int KTILES = HDIM / BK;  // 16

typedef __attribute__((ext_vector_type(4))) int i32x4;
typedef __attribute__((ext_vector_type(16))) int i32x16;

// ---------- prep: per-row i8 quant (tiled+swizzled layout); bias ----------
__global__ void prep_kernel(const float* __restrict__ A, const float* __restrict__ W,
                            const float* __restrict__ E, const float* __restrict__ b,
                            signed char* __restrict__ Aq, signed char* __restrict__ Wq,
                            float* __restrict__ sA, float* __restrict__ sW,
                            float* __restrict__ bias) {
  const int bid = blockIdx.x;
  const int w = threadIdx.x >> 6;
  const int l = threadIdx.x & 63;
  const bool isW = bid < (LDIM / 4);
  const int row = isW ? bid * 4 + w : (bid - LDIM / 4) * 4 + w;
  const float4* s4 = (const float4*)((isW ? W : A) + (size_t)row * HDIM);

  float4 v[4];
  float amax = 0.f, dot = 0.f;
#pragma unroll
  for (int i = 0; i < 4; ++i) {
    v[i] = s4[i * 64 + l];
    amax = fmaxf(amax, fmaxf(fmaxf(fabsf(v[i].x), fabsf(v[i].y)),
                             fmaxf(fabsf(v[i].z), fabsf(v[i].w))));
  }
  if (isW) {
    const float4* e4 = (const float4*)(E + (size_t)row * HDIM);
#pragma unroll
    for (int i = 0; i < 4; ++i) {
      float4 ev = e4[i * 64 + l];
      dot += v[i].x * ev.x + v[i].y * ev.y + v[i].z * ev.z + v[i].w * ev.w;
    }
  }
#pragma unroll
  for (int o = 32; o > 0; o >>= 1) amax = fmaxf(amax, __shfl_xor(amax, o, 64));
  if (isW) {
#pragma unroll
    for (int o = 32; o > 0; o >>= 1) dot += __shfl_xor(dot, o, 64);
  }
  const float inv = amax > 0.f ? 127.f / amax : 0.f;

  // tiled + pre-swizzled store: panel P (PS rows), row-in-panel rin,
  // k-tile t (64B slice), 16B-subchunk sub at slot (sub ^ ((rin>>1)&3)).
  const int PS = isW ? BN : BM;
  const int P = isW ? (row >> 7) : (row >> 8);
  const int rin = row & (PS - 1);
  const int key = (rin >> 1) & 3;
  unsigned int* dstb = (unsigned int*)(isW ? Wq : Aq);
  const size_t pbase = (size_t)P * 16 * PS * 16;  // dwords per panel
#pragma unroll
  for (int i = 0; i < 4; ++i) {
    int q0 = (int)rintf(v[i].x * inv), q1 = (int)rintf(v[i].y * inv);
    int q2 = (int)rintf(v[i].z * inv), q3 = (int)rintf(v[i].w * inv);
    unsigned int packed =
        (q0 & 255) | ((q1 & 255) << 8) | ((q2 & 255) << 16) | ((q3 & 255) << 24);
    const int d = i * 64 + l;          // original dword index in row (0..255)
    const int t = d >> 4;              // k-tile 0..15
    const int dw = d & 15;             // dword within 64B slice
    const int sub = ((dw >> 2) ^ key); // swizzled 16B slot
    dstb[pbase + ((size_t)t * PS + rin) * 16 + sub * 4 + (dw & 3)] = packed;
  }
  if (l == 0) {
    if (isW) { sW[row] = amax * (1.f / 127.f); bias[row] = dot + b[row]; }
    else sA[row] = amax * (1.f / 127.f);
  }
}

// ---------- GEMM: C[B,L] = sA*sW*(Aq . Wq^T) + bias[L] ----------
__device__ __forceinline__ void gld_lds16(const void* g, void* l) {
  __builtin_amdgcn_global_load_lds(
      (const __attribute__((address_space(1))) void*)g,
      (__attribute__((address_space(3))) void*)l, 16, 0, 0);
}

#define MEMPIN asm volatile("" ::: "memory")
#define SCHED0 __builtin_amdgcn_sched_barrier(0)
#define BAR __builtin_amdgcn_s_barrier()
#define LGKM0 asm volatile("s_waitcnt lgkmcnt(0)" ::: "memory")
#define VM6 asm volatile("s_waitcnt vmcnt(6)" ::: "memory")
#define VM0 asm volatile("s_waitcnt vmcnt(0)" ::: "memory")
#define VMNONE (void)0

__global__ __launch_bounds__(256, 2) void gemm_kernel(
    const signed char* __restrict__ Aq,  // tiled [64][16][256][64]
    const signed char* __restrict__ Wq,  // tiled [32][16][128][64]
    const float* __restrict__ sA,        // [BDIM]
    const float* __restrict__ sW,        // [LDIM]
    const float* __restrict__ bias,      // [LDIM]
    float* __restrict__ C)               // [BDIM, LDIM]
{
  // As: 3 x 16KB ring. Bs: 3 x 8KB ring. 72 KiB -> 2 blocks/CU.
  __shared__ __attribute__((aligned(128))) signed char As[3 * BM * BK];
  __shared__ __attribute__((aligned(128))) signed char Bs[3 * BN * BK];

  const int tid = threadIdx.x;
  const int w = tid >> 6;      // wave 0..3
  const int l = tid & 63;
  const int wr = w >> 1;       // 0..1 : M half (128 rows)
  const int wc = w & 1;        // 0..1 : N half (64 cols)
  const int l31 = l & 31;
  const int hi5 = l >> 5;

  // XCD-aware swizzle (2048 blocks, %8==0 -> bijective), nblk inner.
  const int bid = blockIdx.x;
  const int swz = (bid & 7) * 256 + (bid >> 3);
  const int mblk = swz >> 5;   // 64
  const int nblk = swz & 31;   // 32
  const int brow = mblk * BM;
  const int bcol = nblk * BN;

  // staging sources: dense panel files; each instruction reads 4KB contiguous.
  const signed char* aFile = Aq + (size_t)mblk * (16 * BM * 64) + tid * 16;
  const signed char* bFile = Wq + (size_t)nblk * (16 * BN * 64) + tid * 16;

  // fragment-read byte offsets (32x32x32 i8, R8-verified mapping):
  // k-step ks (K=32), lane half hi5 -> source chunk ks*2+hi5, XOR key
  // (l31>>1)&3 (row bases are multiples of 32 -> key depends on l31 only).
  const int csw = (l31 >> 1) & 3;
  const int c0 = ((0 + hi5) ^ csw) * 16;  // ks=0
  const int c1 = ((2 + hi5) ^ csw) * 16;  // ks=1

  i32x16 acc[4][2] = {};  // [m-frag 32r][n-frag 32c]
  i32x4 aF0[4], aF1[4], bF0[2], bF1[2];

  // A k-tile = 16KB dense: 4 instrs of 4KB. B k-tile = 8KB: 2 instrs.
#define ISSUE_A(s, kk)                                                         \
  { const signed char* s_ = aFile + (size_t)(kk) * (BM * 64);                  \
    _Pragma("unroll") for (int i = 0; i < 4; ++i)                              \
      gld_lds16(s_ + i * 4096, &As[(s) * 16384 + i * 4096 + w * 1024]); }
#define ISSUE_B(s, kk)                                                         \
  { const signed char* s_ = bFile + (size_t)(kk) * (BN * 64);                  \
    _Pragma("unroll") for (int i = 0; i < 2; ++i)                              \
      gld_lds16(s_ + i * 4096, &Bs[(s) * 8192 + i * 4096 + w * 1024]); }

#define READ_AB(s)                                                             \
  _Pragma("unroll") for (int mf = 0; mf < 4; ++mf) {                           \
    const int r_ = (s) * 16384 + (wr * 128 + mf * 32 + l31) * 64;              \
    aF0[mf] = *(const i32x4*)&As[r_ + c0];                                     \
    aF1[mf] = *(const i32x4*)&As[r_ + c1];                                     \
  }                                                                            \
  _Pragma("unroll") for (int nf = 0; nf < 2; ++nf) {                           \
    const int r_ = (s) * 8192 + (wc * 64 + nf * 32 + l31) * 64;                \
    bF0[nf] = *(const i32x4*)&Bs[r_ + c0];                                     \
    bF1[nf] = *(const i32x4*)&Bs[r_ + c1];                                     \
  }

#define MFMA16X                                                                \
  _Pragma("unroll") for (int mf = 0; mf < 4; ++mf) {                           \
    _Pragma("unroll") for (int nf = 0; nf < 2; ++nf) {                         \
      acc[mf][nf] = __builtin_amdgcn_mfma_i32_32x32x32_i8(                     \
          aF0[mf], bF0[nf], acc[mf][nf], 0, 0, 0);                             \
      acc[mf][nf] = __builtin_amdgcn_mfma_i32_32x32x32_i8(                     \
          aF1[mf], bF1[nf], acc[mf][nf], 0, 0, 0);                             \
    }                                                                          \
  }

  // region t (read slot s=t%3): issue tile t+2 -> slot (t+2)%3 (6 loads, 2
  // regions of slack); ds_read; lgkm0; 16 MFMA; vmcnt(6) (tile t+1 landed);
  // ONE barrier. Slots disjoint mod 3; drift bounded by the barrier.
#define REGION(s, s2, SS, kk2, VMW, DOBAR)                                     \
  { READ_AB(s)                                                                 \
    if (SS) { ISSUE_A((s2), (kk2)); ISSUE_B((s2), (kk2)); }                    \
    SCHED0; LGKM0; SCHED0;                                                     \
    __builtin_amdgcn_s_setprio(1);                                             \
    MFMA16X                                                                    \
    __builtin_amdgcn_s_setprio(0);                                             \
    SCHED0;                                                                    \
    VMW; MEMPIN;                                                               \
    if (DOBAR) BAR;                                                            \
    MEMPIN; }

  // prologue: tiles 0,1 -> slots 0,1; vm6 -> tile 0 landed.
  ISSUE_A(0, 0); ISSUE_B(0, 0);
  ISSUE_A(1, 1); ISSUE_B(1, 1);
  VM6;
  MEMPIN; BAR;

#pragma unroll 1
  for (int t = 0; t < 12; t += 3) {
    REGION(0, 2, 1, t + 2, VM6, 1);
    REGION(1, 0, 1, t + 3, VM6, 1);
    REGION(2, 1, 1, t + 4, VM6, 1);
  }
  REGION(0, 2, 1, 14, VM6, 1);
  REGION(1, 0, 1, 15, VM6, 1);
  REGION(2, 0, 0, 0, VM0, 1);
  REGION(0, 0, 0, 0, VMNONE, 0);

  // epilogue (R8-verified 32x32 C/D layout): col = l31, row =
  // (reg&3) + 8*(reg>>2) + 4*hi5 within the 32x32 fragment.
  float sw2[2], bv2[2];
#pragma unroll
  for (int nf = 0; nf < 2; ++nf) {
    const int cc = bcol + wc * 64 + nf * 32 + l31;
    sw2[nf] = sW[cc];
    bv2[nf] = bias[cc];
  }
  const int ocol = bcol + wc * 64 + l31;
#pragma unroll
  for (int mf = 0; mf < 4; ++mf) {
    const int rb = brow + wr * 128 + mf * 32 + hi5 * 4;
#pragma unroll
    for (int reg = 0; reg < 16; ++reg) {
      const int row = rb + (reg & 3) + 8 * (reg >> 2);
      const float sa = sA[row];
      const size_t off = (size_t)row * LDIM + ocol;
      C[off]      = (float)acc[mf][0][reg] * (sa * sw2[0]) + bv2[0];
      C[off + 32] = (float)acc[mf][1][reg] * (sa * sw2[1]) + bv2[1];
    }
  }
#undef REGION
#undef MFMA16X
#undef READ_AB
#undef ISSUE_A
#undef ISSUE_B
}

extern "C" void kernel_launch(void* const* d_in, const int* in_sizes, int n_in,
                              void* d_out, int out_size, void* d_ws, size_t ws_size,
                              hipStream_t stream) {
  const float* bert = (const float*)d_in[0];  // [B,H]
  const float* emb  = (const float*)d_in[1];  // [L,H]
  const float* W    = (const float*)d_in[2];  // [L,H]
  const float* b    = (const float*)d_in[3];  // [L]
  float* out = (float*)d_out;

  // ws layout: Aq 16MB | Wq 4MB | sA 64KB | sW 16KB | bias 16KB
  char* ws = (char*)d_ws;
  signed char* Aq = (signed char*)ws;
  signed char* Wq = (signed char*)(ws + (size_t)BDIM * HDIM);
  float* sAp  = (float*)(ws + (size_t)BDIM * HDIM + (size_t)LDIM * HDIM);
  float* sWp  = (float*)((char*)sAp + BDIM * sizeof(float));
  float* bias = (float*)((char*)sWp + LDIM * sizeof(float));

  hipLaunchKernelGGL(prep_kernel, dim3(LDIM / 4 + BDIM / 4), dim3(256), 0, stream,
                     bert, W, emb, b, Aq, Wq, sAp, sWp, bias);
  hipLaunchKernelGGL(gemm_kernel, dim3((BDIM / BM) * (LDIM / BN)), dim3(256), 0, stream,
                     Aq, Wq, sAp, sWp, bias, out);
}

// Round 17
// 126.964 us; speedup vs baseline: 1.0862x; 1.0862x over previous
//
#include <hip/hip_runtime.h>
#include <hip/hip_bf16.h>

// Problem dims
constexpr int BDIM = 16384;  // B (GEMM M)
constexpr int LDIM = 4096;   // L (GEMM N)
constexpr int HDIM = 1024;   // H (GEMM K)

// R13 (best validated: 128.3 us). GEMM tile: 256x128, BK=64 (i8), 256 thr =
// 4 waves (2Mx2N), wave tile 128x64, mfma_i32_16x16x64_i8.
// A,B in 3-slot LDS rings, distance-2 staging, vmcnt(6), ONE barrier/K-tile.
// Aq/Wq panel-major tiled + pre-swizzled: staging reads 4KB contiguous.
// Direct dequant epilogue (validated race-free incl. post-timing replay).
constexpr int BM = 256;
constexpr int BN = 128;
constexpr int BK = 64;
constexpr int KTILES = HDIM / BK;  // 16

typedef __attribute__((ext_vector_type(4))) int i32x4;

// ---------- prep: per-row i8 quant (tiled+swizzled layout); bias ----------
__global__ void prep_kernel(const float* __restrict__ A, const float* __restrict__ W,
                            const float* __restrict__ E, const float* __restrict__ b,
                            signed char* __restrict__ Aq, signed char* __restrict__ Wq,
                            float* __restrict__ sA, float* __restrict__ sW,
                            float* __restrict__ bias) {
  const int bid = blockIdx.x;
  const int w = threadIdx.x >> 6;
  const int l = threadIdx.x & 63;
  const bool isW = bid < (LDIM / 4);
  const int row = isW ? bid * 4 + w : (bid - LDIM / 4) * 4 + w;
  const float4* s4 = (const float4*)((isW ? W : A) + (size_t)row * HDIM);

  float4 v[4];
  float amax = 0.f, dot = 0.f;
#pragma unroll
  for (int i = 0; i < 4; ++i) {
    v[i] = s4[i * 64 + l];
    amax = fmaxf(amax, fmaxf(fmaxf(fabsf(v[i].x), fabsf(v[i].y)),
                             fmaxf(fabsf(v[i].z), fabsf(v[i].w))));
  }
  if (isW) {
    const float4* e4 = (const float4*)(E + (size_t)row * HDIM);
#pragma unroll
    for (int i = 0; i < 4; ++i) {
      float4 ev = e4[i * 64 + l];
      dot += v[i].x * ev.x + v[i].y * ev.y + v[i].z * ev.z + v[i].w * ev.w;
    }
  }
#pragma unroll
  for (int o = 32; o > 0; o >>= 1) amax = fmaxf(amax, __shfl_xor(amax, o, 64));
  if (isW) {
#pragma unroll
    for (int o = 32; o > 0; o >>= 1) dot += __shfl_xor(dot, o, 64);
  }
  const float inv = amax > 0.f ? 127.f / amax : 0.f;

  // tiled + pre-swizzled store: panel P (PS rows), row-in-panel rin,
  // k-tile t (64B slice), 16B-subchunk sub at slot (sub ^ ((rin>>1)&3)).
  const int PS = isW ? BN : BM;
  const int P = isW ? (row >> 7) : (row >> 8);
  const int rin = row & (PS - 1);
  const int key = (rin >> 1) & 3;
  unsigned int* dstb = (unsigned int*)(isW ? Wq : Aq);
  const size_t pbase = (size_t)P * 16 * PS * 16;  // dwords per panel
#pragma unroll
  for (int i = 0; i < 4; ++i) {
    int q0 = (int)rintf(v[i].x * inv), q1 = (int)rintf(v[i].y * inv);
    int q2 = (int)rintf(v[i].z * inv), q3 = (int)rintf(v[i].w * inv);
    unsigned int packed =
        (q0 & 255) | ((q1 & 255) << 8) | ((q2 & 255) << 16) | ((q3 & 255) << 24);
    const int d = i * 64 + l;          // original dword index in row (0..255)
    const int t = d >> 4;              // k-tile 0..15
    const int dw = d & 15;             // dword within 64B slice
    const int sub = ((dw >> 2) ^ key); // swizzled 16B slot
    dstb[pbase + ((size_t)t * PS + rin) * 16 + sub * 4 + (dw & 3)] = packed;
  }
  if (l == 0) {
    if (isW) { sW[row] = amax * (1.f / 127.f); bias[row] = dot + b[row]; }
    else sA[row] = amax * (1.f / 127.f);
  }
}

// ---------- GEMM: C[B,L] = sA*sW*(Aq . Wq^T) + bias[L] ----------
__device__ __forceinline__ void gld_lds16(const void* g, void* l) {
  __builtin_amdgcn_global_load_lds(
      (const __attribute__((address_space(1))) void*)g,
      (__attribute__((address_space(3))) void*)l, 16, 0, 0);
}

#define MEMPIN asm volatile("" ::: "memory")
#define SCHED0 __builtin_amdgcn_sched_barrier(0)
#define BAR __builtin_amdgcn_s_barrier()
#define LGKM0 asm volatile("s_waitcnt lgkmcnt(0)" ::: "memory")
#define VM6 asm volatile("s_waitcnt vmcnt(6)" ::: "memory")
#define VM0 asm volatile("s_waitcnt vmcnt(0)" ::: "memory")
#define VMNONE (void)0

__global__ __launch_bounds__(256, 2) void gemm_kernel(
    const signed char* __restrict__ Aq,  // tiled [64][16][256][64]
    const signed char* __restrict__ Wq,  // tiled [32][16][128][64]
    const float* __restrict__ sA,        // [BDIM]
    const float* __restrict__ sW,        // [LDIM]
    const float* __restrict__ bias,      // [LDIM]
    float* __restrict__ C)               // [BDIM, LDIM]
{
  // As: 3 x 16KB ring. Bs: 3 x 8KB ring. 72 KiB -> 2 blocks/CU.
  __shared__ __attribute__((aligned(128))) signed char As[3 * BM * BK];
  __shared__ __attribute__((aligned(128))) signed char Bs[3 * BN * BK];

  const int tid = threadIdx.x;
  const int w = tid >> 6;      // wave 0..3
  const int l = tid & 63;
  const int wr = w >> 1;       // 0..1 : M half (128 rows)
  const int wc = w & 1;        // 0..1 : N half (64 cols)
  const int lr = l & 15;
  const int hi = l >> 4;

  // XCD-aware swizzle (2048 blocks, %8==0 -> bijective), nblk inner.
  const int bid = blockIdx.x;
  const int swz = (bid & 7) * 256 + (bid >> 3);
  const int mblk = swz >> 5;   // 64
  const int nblk = swz & 31;   // 32
  const int brow = mblk * BM;
  const int bcol = nblk * BN;

  // staging sources: dense panel files; each instruction reads 4KB contiguous.
  const signed char* aFile = Aq + (size_t)mblk * (16 * BM * 64) + tid * 16;
  const signed char* bFile = Wq + (size_t)nblk * (16 * BN * 64) + tid * 16;

  // fragment-read byte offset within a 64B row (XOR read side)
  const int c0 = (hi ^ ((lr >> 1) & 3)) * 16;

  i32x4 acc[8][4] = {};
  i32x4 aF[8], bF[4];

  // A k-tile = 16KB dense: 4 instrs of 4KB. B k-tile = 8KB: 2 instrs.
#define ISSUE_A(s, kk)                                                         \
  { const signed char* s_ = aFile + (size_t)(kk) * (BM * 64);                  \
    _Pragma("unroll") for (int i = 0; i < 4; ++i)                              \
      gld_lds16(s_ + i * 4096, &As[(s) * 16384 + i * 4096 + w * 1024]); }
#define ISSUE_B(s, kk)                                                         \
  { const signed char* s_ = bFile + (size_t)(kk) * (BN * 64);                  \
    _Pragma("unroll") for (int i = 0; i < 2; ++i)                              \
      gld_lds16(s_ + i * 4096, &Bs[(s) * 8192 + i * 4096 + w * 1024]); }

#define READ_AB(s)                                                             \
  _Pragma("unroll") for (int mi = 0; mi < 8; ++mi)                             \
    aF[mi] = *(const i32x4*)&As[(s) * 16384 +                                  \
                                (wr * 128 + mi * 16 + lr) * 64 + c0];          \
  _Pragma("unroll") for (int ni = 0; ni < 4; ++ni)                             \
    bF[ni] = *(const i32x4*)&Bs[(s) * 8192 +                                   \
                                (wc * 64 + ni * 16 + lr) * 64 + c0];

#define MFMA32                                                                 \
  _Pragma("unroll") for (int mi = 0; mi < 8; ++mi) {                           \
    _Pragma("unroll") for (int ni = 0; ni < 4; ++ni) {                         \
      acc[mi][ni] = __builtin_amdgcn_mfma_i32_16x16x64_i8(                     \
          aF[mi], bF[ni], acc[mi][ni], 0, 0, 0);                               \
    }                                                                          \
  }

#define REGION(s, s2, SS, kk2, VMW, DOBAR)                                     \
  { READ_AB(s)                                                                 \
    if (SS) { ISSUE_A((s2), (kk2)); ISSUE_B((s2), (kk2)); }                    \
    SCHED0; LGKM0; SCHED0;                                                     \
    __builtin_amdgcn_s_setprio(1);                                             \
    MFMA32                                                                     \
    __builtin_amdgcn_s_setprio(0);                                             \
    SCHED0;                                                                    \
    VMW; MEMPIN;                                                               \
    if (DOBAR) BAR;                                                            \
    MEMPIN; }

  // prologue: tiles 0,1 -> slots 0,1; vm6 -> tile 0 landed.
  ISSUE_A(0, 0); ISSUE_B(0, 0);
  ISSUE_A(1, 1); ISSUE_B(1, 1);
  VM6;
  MEMPIN; BAR;

#pragma unroll 1
  for (int t = 0; t < 12; t += 3) {
    REGION(0, 2, 1, t + 2, VM6, 1);
    REGION(1, 0, 1, t + 3, VM6, 1);
    REGION(2, 1, 1, t + 4, VM6, 1);
  }
  REGION(0, 2, 1, 14, VM6, 1);
  REGION(1, 0, 1, 15, VM6, 1);
  REGION(2, 0, 0, 0, VM0, 1);
  REGION(0, 0, 0, 0, VMNONE, 0);

  // epilogue: dequant out = sA[r]*sW[c]*acc + bias[c]
  float sw4[4], bv[4];
#pragma unroll
  for (int ni = 0; ni < 4; ++ni) {
    const int cc = bcol + wc * 64 + ni * 16 + lr;
    sw4[ni] = sW[cc];
    bv[ni] = bias[cc];
  }
  const int orow0 = brow + wr * 128 + hi * 4;
  const int ocol0 = bcol + wc * 64 + lr;
#pragma unroll
  for (int mi = 0; mi < 8; ++mi) {
#pragma unroll
    for (int r = 0; r < 4; ++r) {
      const float sa = sA[orow0 + mi * 16 + r];
#pragma unroll
      for (int ni = 0; ni < 4; ++ni) {
        C[(size_t)(orow0 + mi * 16 + r) * LDIM + ocol0 + ni * 16] =
            (float)acc[mi][ni][r] * (sa * sw4[ni]) + bv[ni];
      }
    }
  }
#undef REGION
#undef MFMA32
#undef READ_AB
#undef ISSUE_A
#undef ISSUE_B
}

extern "C" void kernel_launch(void* const* d_in, const int* in_sizes, int n_in,
                              void* d_out, int out_size, void* d_ws, size_t ws_size,
                              hipStream_t stream) {
  const float* bert = (const float*)d_in[0];  // [B,H]
  const float* emb  = (const float*)d_in[1];  // [L,H]
  const float* W    = (const float*)d_in[2];  // [L,H]
  const float* b    = (const float*)d_in[3];  // [L]
  float* out = (float*)d_out;

  // ws layout: Aq 16MB | Wq 4MB | sA 64KB | sW 16KB | bias 16KB
  char* ws = (char*)d_ws;
  signed char* Aq = (signed char*)ws;
  signed char* Wq = (signed char*)(ws + (size_t)BDIM * HDIM);
  float* sAp  = (float*)(ws + (size_t)BDIM * HDIM + (size_t)LDIM * HDIM);
  float* sWp  = (float*)((char*)sAp + BDIM * sizeof(float));
  float* bias = (float*)((char*)sWp + LDIM * sizeof(float));

  hipLaunchKernelGGL(prep_kernel, dim3(LDIM / 4 + BDIM / 4), dim3(256), 0, stream,
                     bert, W, emb, b, Aq, Wq, sAp, sWp, bias);
  hipLaunchKernelGGL(gemm_kernel, dim3((BDIM / BM) * (LDIM / BN)), dim3(256), 0, stream,
                     Aq, Wq, sAp, sWp, bias, out);
}